// Round 1
// baseline (1075.697 us; speedup 1.0000x reference)
//
#include <hip/hip_runtime.h>
#include <stdint.h>

#define G3          (256 * 256 * 256)        // 16,777,216 cells per cascade
#define CASCADES    3
#define NUM_COORDS  (G3 / 4)                 // 4,194,304 (= 1 << 22)
#define GRID_ELEMS  (CASCADES * G3)          // 50,331,648
#define BF_ELEMS    (GRID_ELEMS / 8)         // 6,291,456

__device__ __forceinline__ uint32_t part1by2(uint32_t x) {
    x &= 0x3FFu;
    x = (x | (x << 16)) & 0x030000FFu;
    x = (x | (x << 8))  & 0x0300F00Fu;
    x = (x | (x << 4))  & 0x030C30C3u;
    x = (x | (x << 2))  & 0x09249249u;
    return x;
}

// Pass 1: zero the tag grid (staged in the new_grid region of d_out).
__global__ void clear_tags(uint32_t* __restrict__ tags) {
    int t = blockIdx.x * blockDim.x + threadIdx.x;   // [0, GRID_ELEMS/4)
    uint4 z = make_uint4(0u, 0u, 0u, 0u);
    ((uint4*)tags)[t] = z;
}

// Pass 2: last-write-wins scatter via order-priority atomicMax(tag = n+1).
// Each thread handles 4 coords (reads 3 x int4 = 48 contiguous bytes).
__global__ void scatter_tags(const int* __restrict__ coords,
                             uint32_t* __restrict__ tags) {
    int t = blockIdx.x * blockDim.x + threadIdx.x;   // [0, CASCADES*NUM_COORDS/4)
    const int4* c4 = (const int4*)coords;
    int4 a = c4[t * 3 + 0];   // x0 y0 z0 x1
    int4 b = c4[t * 3 + 1];   // y1 z1 x2 y2
    int4 c = c4[t * 3 + 2];   // z2 x3 y3 z3

    int g    = t * 4;                       // global coord index
    int casc = g >> 22;                     // / NUM_COORDS
    uint32_t n0 = (uint32_t)(g & (NUM_COORDS - 1));
    uint32_t* tg = tags + (size_t)casc * G3;

    uint32_t i0 = part1by2((uint32_t)a.x) | (part1by2((uint32_t)a.y) << 1) | (part1by2((uint32_t)a.z) << 2);
    uint32_t i1 = part1by2((uint32_t)a.w) | (part1by2((uint32_t)b.x) << 1) | (part1by2((uint32_t)b.y) << 2);
    uint32_t i2 = part1by2((uint32_t)b.z) | (part1by2((uint32_t)b.w) << 1) | (part1by2((uint32_t)c.x) << 2);
    uint32_t i3 = part1by2((uint32_t)c.y) | (part1by2((uint32_t)c.z) << 1) | (part1by2((uint32_t)c.w) << 2);

    atomicMax(&tg[i0], n0 + 1u);
    atomicMax(&tg[i1], n0 + 2u);
    atomicMax(&tg[i2], n0 + 3u);
    atomicMax(&tg[i3], n0 + 4u);
}

// Pass 3: in-place combine + bitfield. Each thread exclusively owns 8 cells
// (one bitfield byte), so reading tags then overwriting with floats is safe.
__global__ void finalize(float* __restrict__ out,
                         const float* __restrict__ density,
                         const float* __restrict__ sigmas) {
    int t = blockIdx.x * blockDim.x + threadIdx.x;   // [0, BF_ELEMS)
    uint4  tg0 = ((const uint4*)out)[t * 2 + 0];
    uint4  tg1 = ((const uint4*)out)[t * 2 + 1];
    float4 d0  = ((const float4*)density)[t * 2 + 0];
    float4 d1  = ((const float4*)density)[t * 2 + 1];

    int cell0 = t * 8;
    int casc  = cell0 >> 24;                 // / G3
    const float* sig = sigmas + (size_t)casc * NUM_COORDS;

    uint32_t tg[8] = {tg0.x, tg0.y, tg0.z, tg0.w, tg1.x, tg1.y, tg1.z, tg1.w};
    float    dd[8] = {d0.x, d0.y, d0.z, d0.w, d1.x, d1.y, d1.z, d1.w};
    float    nv[8];
    uint32_t byte = 0u;

#pragma unroll
    for (int i = 0; i < 8; ++i) {
        float d = dd[i];
        float v = d;
        uint32_t tag = tg[i];
        if (tag != 0u) {
            float s = sig[tag - 1u];         // sigma * DENSITY_SCALE(=1.0)
            if (d >= 0.0f && s >= 0.0f) {    // valid = (old>=0) & (temp>=0)
                v = fmaxf(d * 0.95f, s);     // max(old*DECAY, temp)
            }
        }
        nv[i] = v;
        byte |= (v > 0.01f ? 1u : 0u) << i;  // bit b of byte = cell 8k+b
    }

    float4 o0 = make_float4(nv[0], nv[1], nv[2], nv[3]);
    float4 o1 = make_float4(nv[4], nv[5], nv[6], nv[7]);
    ((float4*)out)[t * 2 + 0] = o0;
    ((float4*)out)[t * 2 + 1] = o1;
    out[GRID_ELEMS + t] = (float)byte;       // bitfield byte as float32
}

extern "C" void kernel_launch(void* const* d_in, const int* in_sizes, int n_in,
                              void* d_out, int out_size, void* d_ws, size_t ws_size,
                              hipStream_t stream) {
    const float* density = (const float*)d_in[0];   // [3, 256^3] f32
    const float* sigmas  = (const float*)d_in[1];   // [3, 2^22]  f32
    const int*   coords  = (const int*)d_in[2];     // [3, 2^22, 3] i32
    float* out = (float*)d_out;                     // 50,331,648 grid + 6,291,456 bitfield floats
    uint32_t* tags = (uint32_t*)d_out;              // tag grid staged in-place

    clear_tags  <<<GRID_ELEMS / 4 / 256,             256, 0, stream>>>(tags);
    scatter_tags<<<CASCADES * NUM_COORDS / 4 / 256,  256, 0, stream>>>(coords, tags);
    finalize    <<<BF_ELEMS / 256,                   256, 0, stream>>>(out, density, sigmas);
}